// Round 7
// baseline (215.740 us; speedup 1.0000x reference)
//
#include <hip/hip_runtime.h>

// Fused: z = x @ W^T + b_lin; y = swish(z) + b_ex; GroupNorm(32 groups) * gn_w + gn_b
// x: [8192, 2048] f32, W: [4096, 2048] f32, out: [8192, 4096] f32
// Round 7: 128x128 tile, BK=32, 4 waves, TRIPLE-buffered LDS (52 KB -> 3
// blocks/CU ~ 12 waves/CU, 3 independent barrier domains). One phase per
// K-tile: {8 ds_read; stage tile t+2 (4 gload_lds); VMC(4); BAR; lgkm0;
// 16 independent MFMA}. Bank swizzle slot^=(row>>1)&3 (2-way = free).

typedef __attribute__((ext_vector_type(8))) short short8;
typedef __attribute__((ext_vector_type(4))) float f32x4;

#define M_DIM 8192
#define N_DIM 4096
#define K_DIM 2048
#define BM 128
#define BN 128
#define BK 32
#define NT (K_DIM / BK)  // 64

#define AS1 __attribute__((address_space(1)))
#define AS3 __attribute__((address_space(3)))

// ---------------- f32 -> bf16 (RNE) convert, 8 elems/thread ----------------
__global__ void f32_to_bf16_k(const float* __restrict__ in, ushort* __restrict__ out, int n8) {
    int i = blockIdx.x * blockDim.x + threadIdx.x;
    if (i >= n8) return;
    const float4* p = (const float4*)in + 2 * (size_t)i;
    float4 a = p[0], b = p[1];
    float v[8] = {a.x, a.y, a.z, a.w, b.x, b.y, b.z, b.w};
    ushort rr[8];
#pragma unroll
    for (int j = 0; j < 8; ++j) {
        unsigned u = __float_as_uint(v[j]);
        rr[j] = (ushort)((u + 0x7fffu + ((u >> 16) & 1u)) >> 16);  // RNE
    }
    uint4 o;
    o.x = (unsigned)rr[0] | ((unsigned)rr[1] << 16);
    o.y = (unsigned)rr[2] | ((unsigned)rr[3] << 16);
    o.z = (unsigned)rr[4] | ((unsigned)rr[5] << 16);
    o.w = (unsigned)rr[6] | ((unsigned)rr[7] << 16);
    ((uint4*)out)[i] = o;
}

// LDS (ushort offsets): buf b in {0,1,2} at b*8192: A [0,4096), B [4096,8192).
// Region: 128 rows x 32 ushorts (64 B rows, 4 x 16B slots).
// slot stored at (row,s) holds global k-chunk s ^ ((row>>1)&3).
// Read (lane h,r) uses slot h ^ ((r>>1)&3): per quarter-wave exactly 2
// lanes/bank => 2-way (free). Stats: float[2][2][128] at ushort offset 24576.

#define BAR() __builtin_amdgcn_s_barrier()
#define LGKM0() do { asm volatile("s_waitcnt lgkmcnt(0)" ::: "memory"); __builtin_amdgcn_sched_barrier(0); } while (0)
#define VMC(n_) do { asm volatile("s_waitcnt vmcnt(" #n_ ")" ::: "memory"); __builtin_amdgcn_sched_barrier(0); } while (0)

__global__ __launch_bounds__(256, 3) void gemm_swish_gn(
    const ushort* __restrict__ xb, const ushort* __restrict__ wb,
    const float* __restrict__ bias_lin, const float* __restrict__ bias_extra,
    const float* __restrict__ gn_w, const float* __restrict__ gn_b,
    float* __restrict__ out)
{
    extern __shared__ __align__(16) ushort lds[];  // 3*8192 tile + 2048 f32 stats

    const int t = threadIdx.x;
    const int w = t >> 6;        // 4 waves: 2M x 2N
    const int l = t & 63;
    const int wm = w >> 1;       // 0..1
    const int wn = w & 1;        // 0..1
    const int h = l >> 4;        // 0..3
    const int r = l & 15;        // 0..15

    // XCD swizzle: 2048 blocks; 8 XCDs as 4x2 grid of 16x16-tile patches.
    const int bid = blockIdx.x;
    const int xcd = bid & 7;
    const int pp = bid >> 3;                      // 0..255
    const int brow = (xcd & 3) * 16 + (pp & 15);  // 0..63
    const int bcol = (xcd >> 2) * 16 + (pp >> 4); // 0..31

    // ---- staging: thread t -> row t>>2 (64-row round), slot t&3; source slot
    // pre-swizzled: s_src = (t&3) ^ sigma(row), sigma(row) = (row>>1)&3 = (t>>3)&3.
    const int srow = t >> 2;
    const int sslot = (t & 3) ^ ((t >> 3) & 3);
    const ushort* pA0 = xb + (size_t)(brow * BM + srow) * K_DIM + sslot * 8;
    const ushort* pA1 = pA0 + (size_t)64 * K_DIM;
    const ushort* pB0 = wb + (size_t)(bcol * BN + srow) * K_DIM + sslot * 8;
    const ushort* pB1 = pB0 + (size_t)64 * K_DIM;
    const int dst = t * 8;

#define STG(P_) do {                                                           \
    __builtin_amdgcn_global_load_lds((const AS1 void*)pA0,                     \
        (AS3 void*)&lds[(P_) * 8192 + dst], 16, 0, 0);                         \
    __builtin_amdgcn_global_load_lds((const AS1 void*)pA1,                     \
        (AS3 void*)&lds[(P_) * 8192 + 2048 + dst], 16, 0, 0);                  \
    __builtin_amdgcn_global_load_lds((const AS1 void*)pB0,                     \
        (AS3 void*)&lds[(P_) * 8192 + 4096 + dst], 16, 0, 0);                  \
    __builtin_amdgcn_global_load_lds((const AS1 void*)pB1,                     \
        (AS3 void*)&lds[(P_) * 8192 + 6144 + dst], 16, 0, 0);                  \
    pA0 += BK; pA1 += BK; pB0 += BK; pB1 += BK; } while (0)

    // ---- fragment read offsets (ushorts): row*32 + (h ^ ((r>>1)&3))*8
    const int slotR = (h ^ ((r >> 1) & 3)) << 3;
    const int aOff = (wm * 64 + r) * 32 + slotR;          // + m*512
    const int bOff = 4096 + (wn * 64 + r) * 32 + slotR;   // + n*512

    f32x4 acc[4][4];
#pragma unroll
    for (int m = 0; m < 4; ++m)
#pragma unroll
        for (int n = 0; n < 4; ++n)
            acc[m][n] = f32x4{0.f, 0.f, 0.f, 0.f};

    // ---- prologue: stage tiles 0,1; gate tile 0; barrier
    STG(0);
    STG(1);
    VMC(4);
    BAR();

    short8 aF[4], bF[4];

    // Phase (tile T, buf P, next-stage buf PN=(P+2)%3):
    // {reads(8); stage T+2 (4); gate; BAR; lgkm0; setprio; 16 MFMA; setprio}
#define PH(P_, PN_, T_)                                                        \
  {                                                                            \
    _Pragma("unroll") for (int m = 0; m < 4; ++m)                              \
        aF[m] = *(const short8*)&lds[(P_) * 8192 + aOff + m * 512];            \
    _Pragma("unroll") for (int n = 0; n < 4; ++n)                              \
        bF[n] = *(const short8*)&lds[(P_) * 8192 + bOff + n * 512];            \
    if ((T_) < NT - 2) { STG(PN_); }                                           \
    if ((T_) >= NT - 2) { VMC(0); } else { VMC(4); }                           \
    BAR(); LGKM0();                                                            \
    __builtin_amdgcn_s_setprio(1);                                             \
    _Pragma("unroll") for (int m = 0; m < 4; ++m)                              \
        _Pragma("unroll") for (int n = 0; n < 4; ++n)                          \
            acc[m][n] = __builtin_amdgcn_mfma_f32_16x16x32_bf16(               \
                aF[m], bF[n], acc[m][n], 0, 0, 0);                             \
    __builtin_amdgcn_s_setprio(0);                                             \
  }

#pragma unroll 1
    for (int tb = 0; tb < NT - 1; tb += 3) {   // 21 iters, t = 0..62
        PH(0, 2, tb);
        PH(1, 0, tb + 1);
        PH(2, 1, tb + 2);
    }
    PH(0, 2, NT - 1);  // t = 63, buf 0

    // ---- epilogue: bias + swish + extra bias; GroupNorm (group == block cols)
    // acc[m][n][j]: row = wm*64 + m*16 + h*4 + j, col = wn*64 + n*16 + r
    const int colbase = bcol * BN + wn * 64;
    float bl[4], be[4], gwv[4], gbv[4];
#pragma unroll
    for (int n = 0; n < 4; ++n) {
        int col = colbase + n * 16 + r;
        bl[n] = bias_lin[col];
        be[n] = bias_extra[col];
        gwv[n] = gn_w[col];
        gbv[n] = gn_b[col];
    }

    float s1[4][4], s2[4][4];
#pragma unroll
    for (int m = 0; m < 4; ++m)
#pragma unroll
        for (int j = 0; j < 4; ++j) { s1[m][j] = 0.f; s2[m][j] = 0.f; }

#pragma unroll
    for (int m = 0; m < 4; ++m)
#pragma unroll
        for (int n = 0; n < 4; ++n)
#pragma unroll
            for (int j = 0; j < 4; ++j) {
                float z = acc[m][n][j] + bl[n];
                float sw = z / (1.f + __expf(-z)) + be[n];
                acc[m][n][j] = sw;
                s1[m][j] += sw;
                s2[m][j] += sw * sw;
            }

#pragma unroll
    for (int mask = 1; mask < 16; mask <<= 1) {
#pragma unroll
        for (int m = 0; m < 4; ++m)
#pragma unroll
            for (int j = 0; j < 4; ++j) {
                s1[m][j] += __shfl_xor(s1[m][j], mask, 16);
                s2[m][j] += __shfl_xor(s2[m][j], mask, 16);
            }
    }

    float* sred = (float*)&lds[24576];  // [2 stat][2 wn][128 rows]
    if (r == 0) {
#pragma unroll
        for (int m = 0; m < 4; ++m)
#pragma unroll
            for (int j = 0; j < 4; ++j) {
                int row = wm * 64 + m * 16 + h * 4 + j;
                sred[(0 * 2 + wn) * 128 + row] = s1[m][j];
                sred[(1 * 2 + wn) * 128 + row] = s2[m][j];
            }
    }
    __syncthreads();

    const size_t orow0 = (size_t)brow * BM;
#pragma unroll
    for (int m = 0; m < 4; ++m)
#pragma unroll
        for (int j = 0; j < 4; ++j) {
            int row = wm * 64 + m * 16 + h * 4 + j;
            float mu = (sred[0 * 128 + row] + sred[1 * 128 + row]) * (1.f / 128.f);
            float ex2 = (sred[2 * 128 + row] + sred[3 * 128 + row]) * (1.f / 128.f);
            float var = ex2 - mu * mu;
            float rs = rsqrtf(var + 1e-5f);
            float* orow = out + (orow0 + row) * N_DIM;
#pragma unroll
            for (int n = 0; n < 4; ++n) {
                int col = colbase + n * 16 + r;
                orow[col] = (acc[m][n][j] - mu) * rs * gwv[n] + gbv[n];
            }
        }
}

extern "C" void kernel_launch(void* const* d_in, const int* in_sizes, int n_in,
                              void* d_out, int out_size, void* d_ws, size_t ws_size,
                              hipStream_t stream) {
    const float* x        = (const float*)d_in[0];
    const float* weight   = (const float*)d_in[1];
    const float* bias_lin = (const float*)d_in[2];
    const float* bias_ex  = (const float*)d_in[3];
    const float* gn_w     = (const float*)d_in[4];
    const float* gn_b     = (const float*)d_in[5];
    float* out = (float*)d_out;

    ushort* xb = (ushort*)d_ws;                     // 32 MiB bf16
    ushort* wb = xb + (size_t)M_DIM * K_DIM;        // 16 MiB bf16

    {
        int n8 = (M_DIM * K_DIM) / 8;
        f32_to_bf16_k<<<n8 / 256, 256, 0, stream>>>(x, xb, n8);
    }
    {
        int n8 = (N_DIM * K_DIM) / 8;
        f32_to_bf16_k<<<n8 / 256, 256, 0, stream>>>(weight, wb, n8);
    }

    // dynamic LDS: 3*8192 ushorts (48 KiB) + 2048 floats stats (4 KiB) + pad
    const size_t ldsB = 3 * 8192 * sizeof(ushort) + 2048 * sizeof(float);
    dim3 grid((M_DIM / BM) * (N_DIM / BN));  // 2048 blocks
    gemm_swish_gn<<<grid, 256, ldsB, stream>>>(xb, wb, bias_lin, bias_ex, gn_w, gn_b, out);
}

// Round 8
// 185.619 us; speedup vs baseline: 1.1623x; 1.1623x over previous
//
#include <hip/hip_runtime.h>

// Fused: z = x @ W^T + b_lin; y = swish(z) + b_ex; GroupNorm(32 groups) * gn_w + gn_b
// x: [8192, 2048] f32, W: [4096, 2048] f32, out: [8192, 4096] f32
// Round 8: R6 structure (1 barrier/phase, counted vmcnt, 0-conflict LDS) with
// ALL sched_barrier(0) pins removed and no explicit lgkmcnt — the compiler
// schedules ds_read<->MFMA finely (m97/m141 lesson). vmcnt gates keep
// ":::memory" only. MFMA clusters reordered kk-outermost.

typedef __attribute__((ext_vector_type(8))) short short8;
typedef __attribute__((ext_vector_type(4))) float f32x4;

#define M_DIM 8192
#define N_DIM 4096
#define K_DIM 2048
#define BM 256
#define BN 256
#define BK 64
#define NT (K_DIM / BK)  // 32

#define AS1 __attribute__((address_space(1)))
#define AS3 __attribute__((address_space(3)))

// ---------------- f32 -> bf16 (RNE) convert, 8 elems/thread ----------------
__global__ void f32_to_bf16_k(const float* __restrict__ in, ushort* __restrict__ out, int n8) {
    int i = blockIdx.x * blockDim.x + threadIdx.x;
    if (i >= n8) return;
    const float4* p = (const float4*)in + 2 * (size_t)i;
    float4 a = p[0], b = p[1];
    float v[8] = {a.x, a.y, a.z, a.w, b.x, b.y, b.z, b.w};
    ushort rr[8];
#pragma unroll
    for (int j = 0; j < 8; ++j) {
        unsigned u = __float_as_uint(v[j]);
        rr[j] = (ushort)((u + 0x7fffu + ((u >> 16) & 1u)) >> 16);  // RNE
    }
    uint4 o;
    o.x = (unsigned)rr[0] | ((unsigned)rr[1] << 16);
    o.y = (unsigned)rr[2] | ((unsigned)rr[3] << 16);
    o.z = (unsigned)rr[4] | ((unsigned)rr[5] << 16);
    o.w = (unsigned)rr[6] | ((unsigned)rr[7] << 16);
    ((uint4*)out)[i] = o;
}

// LDS: 2 buffers x 64KB. Buffer (ushort offsets): A [0,16384), B [16384,32768);
// 256 rows x 64 ushorts (128B rows, kk0|kk1 halves in-row).
// Read swizzle: 16B-slot = (kk*4+h) ^ (r&7)  [R2/R5/R6-proven 0-conflict].
// Staged linearly (global_load_lds); global SOURCE col pre-swizzled.

#define BAR() __builtin_amdgcn_s_barrier()
#define VMC(n_) asm volatile("s_waitcnt vmcnt(" #n_ ")" ::: "memory")

__global__ __launch_bounds__(512, 2) void gemm_swish_gn(
    const ushort* __restrict__ xb, const ushort* __restrict__ wb,
    const float* __restrict__ bias_lin, const float* __restrict__ bias_extra,
    const float* __restrict__ gn_w, const float* __restrict__ gn_b,
    float* __restrict__ out)
{
    extern __shared__ __align__(16) ushort lds[];  // 2 x 32768 ushorts

    const int t = threadIdx.x;
    const int w = t >> 6;
    const int l = t & 63;
    const int wm = w >> 2;   // 0..1
    const int wn = w & 3;    // 0..3
    const int h = l >> 4;    // 0..3
    const int r = l & 15;    // 0..15

    // T1: XCD swizzle (512 blocks, bijective)
    const int bid = blockIdx.x;
    const int id = (bid & 7) * 64 + (bid >> 3);
    const int brow = id & 31;   // M tile
    const int bcol = id >> 5;   // N tile (= 2 GroupNorm groups)

    // ---- staging: thread t covers row s=t>>3 (per 64-row round), 16B slot t&7,
    // source col pre-swizzled by slot ^= (row&7).
    const int s = t >> 3;
    const int scol = (((t & 7) ^ (s & 7)) << 3);            // ushorts
    const ushort* pA = xb + (size_t)(brow * BM + s) * K_DIM + scol;
    const int rB = (s & 31) + ((s >> 5) << 6);              // B scattered rows
    const ushort* pB = wb + (size_t)(bcol * BN + rB) * K_DIM + scol;
    const int dstA = t * 8;
    const int dstB = rB * 64 + ((t & 7) << 3);

    // chunk rounds: A-lo ROFF {0,128}; A-hi {64,192}; B-lo {0,128}; B-hi {32,160}
#define STG_A(P, ROFF) __builtin_amdgcn_global_load_lds(                         \
        (const AS1 void*)(pA + (size_t)(ROFF) * K_DIM),                          \
        (AS3 void*)&lds[(P) * 32768 + (ROFF) * 64 + dstA], 16, 0, 0)
#define STG_B(P, ROFF) __builtin_amdgcn_global_load_lds(                         \
        (const AS1 void*)(pB + (size_t)(ROFF) * K_DIM),                          \
        (AS3 void*)&lds[(P) * 32768 + 16384 + (ROFF) * 64 + dstB], 16, 0, 0)

    // fragment read offsets (ushorts): row*64 + ((kk*32 + h*8) ^ (r&7)*8)
    const int xr8 = (r & 7) << 3;
    const int aOff0 = (wm * 128 + r) * 64 + ((h << 3) ^ xr8);
    const int aOff1 = aOff0 ^ 32;
    const int bOff0 = 16384 + (wn * 64 + r) * 64 + ((h << 3) ^ xr8);
    const int bOff1 = bOff0 ^ 32;

    f32x4 acc[8][4];
#pragma unroll
    for (int m = 0; m < 8; ++m)
#pragma unroll
        for (int n = 0; n < 4; ++n)
            acc[m][n] = f32x4{0.f, 0.f, 0.f, 0.f};

    // ---- prologue: stage tile 0 (issue order Alo, Blo, Bhi, Ahi), gate, BAR
    STG_A(0, 0); STG_A(0, 128);   // Alo
    STG_B(0, 0); STG_B(0, 128);   // Blo
    STG_B(0, 32); STG_B(0, 160);  // Bhi
    STG_A(0, 64); STG_A(0, 192);  // Ahi
    pA += BK; pB += BK;
    VMC(4);                        // Alo0, Blo0 landed
    BAR();

    short8 aF[4][2], bF[4][2];

#define MFMA(mm, nn, kk, ai) \
    acc[mm][nn] = __builtin_amdgcn_mfma_f32_16x16x32_bf16(aF[ai][kk], bF[nn][kk], acc[mm][nn], 0, 0, 0)

    // Phase = { reads(this); stage(next tile); gate; BAR; setprio; 16 MFMA }.
    // Stage order per tile: ph1 Alo', ph2 Blo'+Bhi', ph3 Ahi'.
    // Gates: ph1 VMC(4), ph2 VMC(6), ph4 VMC(4); tail: VMC(2)/VMC(0)/none.
    // MFMA clusters kk-outermost (dependent same-acc pairs 8 apart).
#define DO_TILE(P, tt)                                                              \
  {                                                                                 \
    /* ---- ph1: reads Alo(m0-3)+Blo(n0-1); stage Alo'; MFMA m0-3 x n0-1 ---- */    \
    _Pragma("unroll") for (int m = 0; m < 4; ++m) {                                 \
        aF[m][0] = *(const short8*)&lds[(P) * 32768 + aOff0 + m * 1024];            \
        aF[m][1] = *(const short8*)&lds[(P) * 32768 + aOff1 + m * 1024];            \
    }                                                                               \
    _Pragma("unroll") for (int n = 0; n < 2; ++n) {                                 \
        bF[n][0] = *(const short8*)&lds[(P) * 32768 + bOff0 + n * 1024];            \
        bF[n][1] = *(const short8*)&lds[(P) * 32768 + bOff1 + n * 1024];            \
    }                                                                               \
    if ((tt) != NT - 1) { STG_A((P) ^ 1, 0); STG_A((P) ^ 1, 128); }                 \
    if ((tt) == NT - 1) { VMC(2); } else { VMC(4); }                                \
    BAR();                                                                          \
    __builtin_amdgcn_s_setprio(1);                                                  \
    _Pragma("unroll") for (int kk = 0; kk < 2; ++kk)                                \
        _Pragma("unroll") for (int m = 0; m < 4; ++m)                               \
            _Pragma("unroll") for (int n = 0; n < 2; ++n)                           \
                MFMA(m, n, kk, m);                                                  \
    __builtin_amdgcn_s_setprio(0);                                                  \
    /* ---- ph2: reads Bhi(n2-3); stage Blo'+Bhi'; MFMA m0-3 x n2-3 ---- */         \
    _Pragma("unroll") for (int n = 2; n < 4; ++n) {                                 \
        bF[n][0] = *(const short8*)&lds[(P) * 32768 + bOff0 + n * 1024];            \
        bF[n][1] = *(const short8*)&lds[(P) * 32768 + bOff1 + n * 1024];            \
    }                                                                               \
    if ((tt) != NT - 1) { STG_B((P) ^ 1, 0); STG_B((P) ^ 1, 128);                   \
                          STG_B((P) ^ 1, 32); STG_B((P) ^ 1, 160); }                \
    if ((tt) == NT - 1) { VMC(0); } else { VMC(6); }                                \
    BAR();                                                                          \
    __builtin_amdgcn_s_setprio(1);                                                  \
    _Pragma("unroll") for (int kk = 0; kk < 2; ++kk)                                \
        _Pragma("unroll") for (int m = 0; m < 4; ++m)                               \
            _Pragma("unroll") for (int n = 2; n < 4; ++n)                           \
                MFMA(m, n, kk, m);                                                  \
    __builtin_amdgcn_s_setprio(0);                                                  \
    /* ---- ph3: reads Ahi(m4-7); stage Ahi'; MFMA m4-7 x n0-1 ---- */              \
    _Pragma("unroll") for (int m = 4; m < 8; ++m) {                                 \
        aF[m - 4][0] = *(const short8*)&lds[(P) * 32768 + aOff0 + m * 1024];        \
        aF[m - 4][1] = *(const short8*)&lds[(P) * 32768 + aOff1 + m * 1024];        \
    }                                                                               \
    if ((tt) != NT - 1) { STG_A((P) ^ 1, 64); STG_A((P) ^ 1, 192);                  \
                          pA += BK; pB += BK; }                                     \
    BAR();                                                                          \
    __builtin_amdgcn_s_setprio(1);                                                  \
    _Pragma("unroll") for (int kk = 0; kk < 2; ++kk)                                \
        _Pragma("unroll") for (int m = 4; m < 8; ++m)                               \
            _Pragma("unroll") for (int n = 0; n < 2; ++n)                           \
                MFMA(m, n, kk, m - 4);                                              \
    __builtin_amdgcn_s_setprio(0);                                                  \
    /* ---- ph4: register-only; gate for next tile's ph1 ---- */                    \
    if ((tt) < NT - 1) { VMC(4); }                                                  \
    BAR();                                                                          \
    __builtin_amdgcn_s_setprio(1);                                                  \
    _Pragma("unroll") for (int kk = 0; kk < 2; ++kk)                                \
        _Pragma("unroll") for (int m = 4; m < 8; ++m)                               \
            _Pragma("unroll") for (int n = 2; n < 4; ++n)                           \
                MFMA(m, n, kk, m - 4);                                              \
    __builtin_amdgcn_s_setprio(0);                                                  \
  }

#pragma unroll 1
    for (int tp = 0; tp < NT; tp += 2) {
        DO_TILE(0, tp);
        DO_TILE(1, tp + 1);
    }

    // ---- epilogue: bias + swish + extra bias, GroupNorm per 128-col group ----
    // acc[m][n][j]: row = wm*128 + m*16 + h*4 + j, col = wn*64 + n*16 + r
    const int colbase = bcol * BN + wn * 64;
    float bl[4], be[4], gwv[4], gbv[4];
#pragma unroll
    for (int n = 0; n < 4; ++n) {
        int col = colbase + n * 16 + r;
        bl[n] = bias_lin[col];
        be[n] = bias_extra[col];
        gwv[n] = gn_w[col];
        gbv[n] = gn_b[col];
    }

    float s1[8][4], s2[8][4];
#pragma unroll
    for (int m = 0; m < 8; ++m)
#pragma unroll
        for (int j = 0; j < 4; ++j) { s1[m][j] = 0.f; s2[m][j] = 0.f; }

#pragma unroll
    for (int m = 0; m < 8; ++m)
#pragma unroll
        for (int n = 0; n < 4; ++n)
#pragma unroll
            for (int j = 0; j < 4; ++j) {
                float z = acc[m][n][j] + bl[n];
                float sw = z / (1.f + __expf(-z)) + be[n];
                acc[m][n][j] = sw;
                s1[m][j] += sw;
                s2[m][j] += sw * sw;
            }

#pragma unroll
    for (int mask = 1; mask < 16; mask <<= 1) {
#pragma unroll
        for (int m = 0; m < 8; ++m)
#pragma unroll
            for (int j = 0; j < 4; ++j) {
                s1[m][j] += __shfl_xor(s1[m][j], mask, 16);
                s2[m][j] += __shfl_xor(s2[m][j], mask, 16);
            }
    }

    __syncthreads();  // all LDS tile reads done before aliasing as stats
    float* sred = (float*)lds;  // [2 stat][2 group-half][2 wave-pair][256 rows]
    const int gh = wn >> 1;
    const int p = wn & 1;
    if (r == 0) {
#pragma unroll
        for (int m = 0; m < 8; ++m)
#pragma unroll
            for (int j = 0; j < 4; ++j) {
                int row = wm * 128 + m * 16 + h * 4 + j;
                sred[((0 * 2 + gh) * 2 + p) * 256 + row] = s1[m][j];
                sred[((1 * 2 + gh) * 2 + p) * 256 + row] = s2[m][j];
            }
    }
    __syncthreads();

    const size_t orow0 = (size_t)brow * BM;
#pragma unroll
    for (int m = 0; m < 8; ++m)
#pragma unroll
        for (int j = 0; j < 4; ++j) {
            int row = wm * 128 + m * 16 + h * 4 + j;
            float mu = (sred[((0 * 2 + gh) * 2 + 0) * 256 + row] +
                        sred[((0 * 2 + gh) * 2 + 1) * 256 + row]) * (1.f / 128.f);
            float ex2 = (sred[((1 * 2 + gh) * 2 + 0) * 256 + row] +
                         sred[((1 * 2 + gh) * 2 + 1) * 256 + row]) * (1.f / 128.f);
            float var = ex2 - mu * mu;
            float rs = rsqrtf(var + 1e-5f);
            float* orow = out + (orow0 + row) * N_DIM;
#pragma unroll
            for (int n = 0; n < 4; ++n) {
                int col = colbase + n * 16 + r;
                orow[col] = (acc[m][n][j] - mu) * rs * gwv[n] + gbv[n];
            }
        }
}

extern "C" void kernel_launch(void* const* d_in, const int* in_sizes, int n_in,
                              void* d_out, int out_size, void* d_ws, size_t ws_size,
                              hipStream_t stream) {
    const float* x        = (const float*)d_in[0];
    const float* weight   = (const float*)d_in[1];
    const float* bias_lin = (const float*)d_in[2];
    const float* bias_ex  = (const float*)d_in[3];
    const float* gn_w     = (const float*)d_in[4];
    const float* gn_b     = (const float*)d_in[5];
    float* out = (float*)d_out;

    ushort* xb = (ushort*)d_ws;                     // 32 MiB bf16
    ushort* wb = xb + (size_t)M_DIM * K_DIM;        // 16 MiB bf16

    {
        int n8 = (M_DIM * K_DIM) / 8;
        f32_to_bf16_k<<<n8 / 256, 256, 0, stream>>>(x, xb, n8);
    }
    {
        int n8 = (N_DIM * K_DIM) / 8;
        f32_to_bf16_k<<<n8 / 256, 256, 0, stream>>>(weight, wb, n8);
    }

    (void)hipFuncSetAttribute((const void*)gemm_swish_gn,
                              hipFuncAttributeMaxDynamicSharedMemorySize, 131072);

    dim3 grid((M_DIM / BM) * (N_DIM / BN));  // 512 blocks
    gemm_swish_gn<<<grid, 512, 131072, stream>>>(xb, wb, bias_lin, bias_ex, gn_w, gn_b, out);
}